// Round 5
// baseline (222.772 us; speedup 1.0000x reference)
//
#include <hip/hip_runtime.h>

// ---------------------------------------------------------------------------
// R_SCNN: two width-direction SCNN scans fused into one 127-step recurrence
// via MFMA (one barrier/step), 1x1-conv channel-dot folded into the scan,
// then 4x bilinear upsample + global BN + sigmoid.
//
//   y_w = c_w + relu(M y_{w-1}),  z_w = y_w + relu(M z_{w-1}),  z_0 = y_0 = c_0
//   s[b,h,p] = dot(v, z_{127-p});  out = sigmoid(BN(upsample4(s)))
//
// Round-5: steady-state steps touch NO global memory. c_w is bulk-staged
// into double-buffered LDS (c[256][16] per 16 steps) with global_load_lds,
// so the compiler's forced `s_waitcnt vmcnt(0)` before each s_barrier (which
// defeated the R4 register prefetch) fires only once per 16 steps — and
// doubles as the chunk-visibility guarantee. k_extract is fused into k_scan
// (A-fragments gathered from conv_w directly); stats+norm fused into one
// kernel with an atomic-counter grid barrier (256 co-resident blocks).
// ---------------------------------------------------------------------------

typedef _Float16 f16x8 __attribute__((ext_vector_type(8)));
typedef _Float16 f16x4 __attribute__((ext_vector_type(4)));
typedef float    f32x4 __attribute__((ext_vector_type(4)));

static __device__ __forceinline__ void load_lds16(const float* g, void* lds) {
  __builtin_amdgcn_global_load_lds(
      (const __attribute__((address_space(1))) void*)g,
      (__attribute__((address_space(3))) void*)lds, 16, 0, 0);
}

// ---- kernel 1: fused extract + double scan via MFMA ------------------------
struct SM {
  _Float16 cy[2][256];        // y carry (f16), ping-pong
  _Float16 pad_[32];          // 64B: cz banks offset 16 vs cy (R4 fix)
  _Float16 cz[2][256];        // z carry (f16), ping-pong
  float    sp[128 * 32];      // s-dot partials [w][32]
  float    cbuf[2][256][16];  // staged c chunks: [chunk&1][ch][wsub]
};

extern "C" __global__ void __launch_bounds__(512, 2)
k_scan(const float* __restrict__ p2, const float* __restrict__ convw,
       const float* __restrict__ conv1, float* __restrict__ sout,
       float* __restrict__ stats, unsigned int* __restrict__ cnt) {
  __shared__ SM sm;
  const int tid  = threadIdx.x;
  const int l    = tid & 63;
  const int r    = tid >> 6;        // wave 0..7
  const int col  = l & 15;          // MFMA n / A-row-within-tile index
  const int quad = l >> 4;          // MFMA k-group / C-row-group index
  const int b    = blockIdx.x >> 6;
  const int h    = blockIdx.x & 63;

  if (blockIdx.x == 0 && tid == 0) { stats[0] = 0.f; stats[1] = 0.f; *cnt = 0u; }

  const bool isY = (col == 0);      // lanes holding C column 0 (y results)
  const bool isZ = (col == 1);      // lanes holding C column 1 (z results)

  // C/D rows owned by this lane: m0..m0+3 (tile 0), m1..m1+3 (tile 1)
  const int m0 = r * 32 + quad * 4;
  const int m1 = m0 + 16;

  // p2_r[b][c][h][w]: channel c at pbase + c*8192 + w
  const float* pbase = p2 + (size_t)b * 2097152 + (size_t)h * 128;

  // ---- stage c chunk 0 (w=0..15) into cbuf[0] ----
#pragma unroll
  for (int j = 0; j < 2; ++j) {
    const float* g = pbase + (size_t)(r * 32 + j * 16 + (l >> 2)) * 8192 + (l & 3) * 4;
    load_lds16(g, &sm.cbuf[0][r * 32 + j * 16][0]);
  }

  // ---- A-fragments straight from conv_w (center tap, stride 9) ----
  // lane holds A[m = tile*16+col][k = ch*32 + quad*8 + j]
  const int row0 = r * 32 + col;
  const int row1 = row0 + 16;
  const int koff = quad * 8;
  f16x8 A0[8], A1[8];
#pragma unroll
  for (int ch = 0; ch < 8; ++ch) {
#pragma unroll
    for (int j = 0; j < 8; ++j) {
      int k = ch * 32 + koff + j;
      A0[ch][j] = (_Float16)convw[(size_t)row0 * 2304 + k * 9 + 4];
      A1[ch][j] = (_Float16)convw[(size_t)row1 * 2304 + k * 9 + 4];
    }
  }

  // ---- init: w=0 state (z_0 = y_0 = c_0) into buffer 0, sp[0], conv1 ----
  float vva[4], vvb[4];               // conv1 weights at owned rows (col1 lanes)
  {
    float c0a[4], c0b[4];
    if (isY || isZ) {
#pragma unroll
      for (int i = 0; i < 4; ++i) {
        c0a[i] = pbase[(size_t)(m0 + i) * 8192];
        c0b[i] = pbase[(size_t)(m1 + i) * 8192];
      }
    }
    if (isY) {
      f16x4 pa, pb;
#pragma unroll
      for (int i = 0; i < 4; ++i) { pa[i] = (_Float16)c0a[i]; pb[i] = (_Float16)c0b[i]; }
      *(f16x4*)(sm.cy[0] + m0) = pa; *(f16x4*)(sm.cy[0] + m1) = pb;
      *(f16x4*)(sm.cz[0] + m0) = pa; *(f16x4*)(sm.cz[0] + m1) = pb;
    }
    if (isZ) {
#pragma unroll
      for (int i = 0; i < 4; ++i) { vva[i] = conv1[m0 + i]; vvb[i] = conv1[m1 + i]; }
      float p = 0.f;
#pragma unroll
      for (int i = 0; i < 4; ++i) p += vva[i] * c0a[i] + vvb[i] * c0b[i];
      sm.sp[0 * 32 + r * 4 + quad] = p;
    }
  }
  __syncthreads();   // drains chunk-0 staging (vmcnt) + carry init (lgkm)

  // B-fragment source: lane parity picks y (even cols) / z (odd cols).
  const _Float16* selA = ((l & 1) ? sm.cz[0] : sm.cy[0]) + quad * 8;  // w odd
  const _Float16* selB = ((l & 1) ? sm.cz[1] : sm.cy[1]) + quad * 8;  // w even

#define STEP(W, SELP, WY, WZ, DOSTAGE)                                         \
  do {                                                                         \
    if (DOSTAGE && ((W) & 15) == 1 && (W) < 113) {                             \
      int t1 = ((W) >> 4) + 1;          /* chunk to stage */                   \
      int bs = t1 & 1;                                                         \
      _Pragma("unroll")                                                        \
      for (int j = 0; j < 2; ++j) {                                            \
        const float* g = pbase + (size_t)(r * 32 + j * 16 + (l >> 2)) * 8192   \
                         + t1 * 16 + (l & 3) * 4;                              \
        load_lds16(g, &sm.cbuf[bs][r * 32 + j * 16][0]);                       \
      }                                                                        \
    }                                                                          \
    f16x8 B[8];                                                                \
    _Pragma("unroll")                                                          \
    for (int ch = 0; ch < 8; ++ch)                                             \
      B[ch] = *(const f16x8*)((SELP) + ch * 32);                               \
    f32x4 a00 = {0.f,0.f,0.f,0.f}, a01 = {0.f,0.f,0.f,0.f};                    \
    f32x4 a10 = {0.f,0.f,0.f,0.f}, a11 = {0.f,0.f,0.f,0.f};                    \
    _Pragma("unroll")                                                          \
    for (int ch = 0; ch < 4; ++ch) {                                           \
      a00 = __builtin_amdgcn_mfma_f32_16x16x32_f16(A0[ch],   B[ch],   a00,0,0,0);\
      a10 = __builtin_amdgcn_mfma_f32_16x16x32_f16(A1[ch],   B[ch],   a10,0,0,0);\
      a01 = __builtin_amdgcn_mfma_f32_16x16x32_f16(A0[ch+4], B[ch+4], a01,0,0,0);\
      a11 = __builtin_amdgcn_mfma_f32_16x16x32_f16(A1[ch+4], B[ch+4], a11,0,0,0);\
    }                                                                          \
    f32x4 acc0 = a00 + a01, acc1 = a10 + a11;                                  \
    const float* cptr = &sm.cbuf[((W) >> 4) & 1][0][(W) & 15];                 \
    f16x4 yh0 = {}, yh1 = {};                                                  \
    if (isY) {                                                                 \
      _Pragma("unroll")                                                        \
      for (int i = 0; i < 4; ++i) {                                            \
        yh0[i] = (_Float16)(cptr[(m0 + i) * 16] + fmaxf(acc0[i], 0.f));        \
        yh1[i] = (_Float16)(cptr[(m1 + i) * 16] + fmaxf(acc1[i], 0.f));        \
      }                                                                        \
      *(f16x4*)((WY) + m0) = yh0;                                              \
      *(f16x4*)((WY) + m1) = yh1;                                              \
    }                                                                          \
    int2 u0 = __builtin_bit_cast(int2, yh0), u1 = __builtin_bit_cast(int2, yh1);\
    u0.x = __shfl(u0.x, l & 62, 64); u0.y = __shfl(u0.y, l & 62, 64);          \
    u1.x = __shfl(u1.x, l & 62, 64); u1.y = __shfl(u1.y, l & 62, 64);          \
    f16x4 ys0 = __builtin_bit_cast(f16x4, u0), ys1 = __builtin_bit_cast(f16x4, u1);\
    if (isZ) {                                                                 \
      f16x4 zh0, zh1;                                                          \
      float p = 0.f;                                                           \
      _Pragma("unroll")                                                        \
      for (int i = 0; i < 4; ++i) {                                            \
        float z0 = (float)ys0[i] + fmaxf(acc0[i], 0.f);                        \
        float z1 = (float)ys1[i] + fmaxf(acc1[i], 0.f);                        \
        zh0[i] = (_Float16)z0; zh1[i] = (_Float16)z1;                          \
        p += vva[i] * z0 + vvb[i] * z1;                                        \
      }                                                                        \
      *(f16x4*)((WZ) + m0) = zh0;                                              \
      *(f16x4*)((WZ) + m1) = zh1;                                              \
      sm.sp[(W) * 32 + r * 4 + quad] = p;                                      \
    }                                                                          \
    __syncthreads();                                                           \
  } while (0)

#pragma unroll 1
  for (int w = 1; w < 127; w += 2) {
    STEP(w,     selA, sm.cy[1], sm.cz[1], 1);  // read buf0, write buf1 (w odd)
    STEP(w + 1, selB, sm.cy[0], sm.cz[0], 0);  // read buf1, write buf0
  }
  STEP(127, selA, sm.cy[1], sm.cz[1], 0);
#undef STEP

  // s[b,h,127-w] = dot(v, z_w): reduce the 32 partials per step
  if (tid < 128) {
    const float4* q = (const float4*)(sm.sp + tid * 32);
    float s = 0.f;
#pragma unroll
    for (int j = 0; j < 8; ++j) { float4 t4 = q[j]; s += t4.x + t4.y + t4.z + t4.w; }
    sout[(blockIdx.x << 7) + (127 - tid)] = s;
  }
}

// ---- bilinear 4x upsample (align_corners) of s: (2,64,128) -> (2,256,512) --
static __device__ __forceinline__ float bilin(const float* __restrict__ s,
                                              int idx) {
  int bb  = idx >> 17;
  int rem = idx & 131071;
  int ho  = rem >> 9;
  int wo  = rem & 511;
  const float SY = 63.0f / 255.0f, SX = 127.0f / 511.0f;
  float fy = (float)ho * SY;
  int y0 = (int)fy; int y1 = min(y0 + 1, 63); float wy = fy - (float)y0;
  float fx = (float)wo * SX;
  int x0 = (int)fx; int x1 = min(x0 + 1, 127); float wx = fx - (float)x0;
  const float* sb = s + bb * 8192;
  float cA = sb[y0 * 128 + x0] * (1.f - wy) + sb[y1 * 128 + x0] * wy;
  float cB = sb[y0 * 128 + x1] * (1.f - wy) + sb[y1 * 128 + x1] * wy;
  return cA * (1.f - wx) + cB * wx;
}

// ---- kernel 2: fused stats + normalize + sigmoid (grid-wide via counter) ---
// 256 blocks x 256 threads (grid <= CU count -> co-resident; spin is safe).
extern "C" __global__ void __launch_bounds__(256, 1)
k_statsnorm(const float* __restrict__ s, float* __restrict__ stats,
            unsigned int* __restrict__ cnt, const float* __restrict__ gamma,
            const float* __restrict__ beta, float* __restrict__ out) {
  int tid  = threadIdx.x;
  int base = blockIdx.x * 1024 + tid;
  float u[4];
  float sum = 0.f, ssq = 0.f;
#pragma unroll
  for (int i = 0; i < 4; ++i) {
    u[i] = bilin(s, base + i * 256);
    sum += u[i]; ssq += u[i] * u[i];
  }
#pragma unroll
  for (int off = 32; off > 0; off >>= 1) {
    sum += __shfl_xor(sum, off, 64);
    ssq += __shfl_xor(ssq, off, 64);
  }
  __shared__ float ls[4], lq[4];
  int wv = tid >> 6;
  if ((tid & 63) == 0) { ls[wv] = sum; lq[wv] = ssq; }
  __syncthreads();
  if (tid == 0) {
    float bsum = ls[0] + ls[1] + ls[2] + ls[3];
    float bssq = lq[0] + lq[1] + lq[2] + lq[3];
    __hip_atomic_fetch_add(&stats[0], bsum, __ATOMIC_RELAXED, __HIP_MEMORY_SCOPE_AGENT);
    __hip_atomic_fetch_add(&stats[1], bssq, __ATOMIC_RELAXED, __HIP_MEMORY_SCOPE_AGENT);
    __hip_atomic_fetch_add(cnt, 1u, __ATOMIC_RELEASE, __HIP_MEMORY_SCOPE_AGENT);
    while (__hip_atomic_load(cnt, __ATOMIC_ACQUIRE, __HIP_MEMORY_SCOPE_AGENT) < 256u)
      __builtin_amdgcn_s_sleep(8);
  }
  __syncthreads();
  float s0 = __hip_atomic_load(&stats[0], __ATOMIC_RELAXED, __HIP_MEMORY_SCOPE_AGENT);
  float s1 = __hip_atomic_load(&stats[1], __ATOMIC_RELAXED, __HIP_MEMORY_SCOPE_AGENT);
  const float invN = 1.f / 262144.f;
  float mean  = s0 * invN;
  float var   = s1 * invN - mean * mean;
  float scale = rsqrtf(var + 1e-5f) * gamma[0];
  float bias  = beta[0] - mean * scale;
#pragma unroll
  for (int i = 0; i < 4; ++i) {
    float x = u[i] * scale + bias;
    out[base + i * 256] = 1.f / (1.f + __expf(-x));
  }
}

// ---------------------------------------------------------------------------
extern "C" void kernel_launch(void* const* d_in, const int* in_sizes, int n_in,
                              void* d_out, int out_size, void* d_ws, size_t ws_size,
                              hipStream_t stream) {
  const float* p2    = (const float*)d_in[0];   // (2,256,64,128)
  const float* convw = (const float*)d_in[1];   // (256,256,1,9)
  const float* conv1 = (const float*)d_in[2];   // (1,256,1,1)
  const float* gamma = (const float*)d_in[3];   // (1,)
  const float* beta  = (const float*)d_in[4];   // (1,)
  float* out = (float*)d_out;                   // (2,1,256,512) fp32

  char* ws = (char*)d_ws;
  float*        s     = (float*)ws;             // 16384 floats  [0, 64KB)
  float*        stats = (float*)(ws + 65536);   // 2 floats
  unsigned int* cnt   = (unsigned int*)(ws + 65544);

  hipLaunchKernelGGL(k_scan,      dim3(128), dim3(512), 0, stream,
                     p2, convw, conv1, s, stats, cnt);
  hipLaunchKernelGGL(k_statsnorm, dim3(256), dim3(256), 0, stream,
                     s, stats, cnt, gamma, beta, out);
}

// Round 6
// 198.338 us; speedup vs baseline: 1.1232x; 1.1232x over previous
//
#include <hip/hip_runtime.h>

// ---------------------------------------------------------------------------
// R_SCNN: two width-direction SCNN scans fused into one 127-step recurrence
// via MFMA (one barrier/step), 1x1-conv channel-dot folded into the scan,
// then 4x bilinear upsample + global BN + sigmoid.
//
//   y_w = c_w + relu(M y_{w-1}),  z_w = y_w + relu(M z_{w-1}),  z_0 = y_0 = c_0
//   s[b,h,p] = dot(v, z_{127-p});  out = sigmoid(BN(upsample4(s)))
//
// Round-6: R4 structure (112us) + steady-state steps with ZERO vmem.
//  - k_extract restored as its own kernel (R5's fused 36B-stride A-gather was
//    L2-BW-bound, ~30-40us startup; dense Md + vector loads is ~1us).
//  - c_w staged per 16 steps into double-buffered PADDED LDS cbuf[2][256][20]
//    (stride 20 floats -> step reads are 2-way-conflict = free; R5's [ch][16]
//    was 4-way on banks {0,16}). Loads issue at step top, ds_writes sink
//    below the MFMA block (~350cyc of latency cover). The compiler's forced
//    `s_waitcnt vmcnt(0)` before s_barrier now fires with vmem in flight only
//    once per 16 steps instead of every step (R4's ~1000cyc/step drain).
//  - w=0 carries initialized from staged chunk 0 (no scattered init loads).
// ---------------------------------------------------------------------------

typedef _Float16 f16x8 __attribute__((ext_vector_type(8)));
typedef _Float16 f16x4 __attribute__((ext_vector_type(4)));
typedef float    f32x4 __attribute__((ext_vector_type(4)));

// ---- kernel 0: extract center tap of conv_w -> dense f16 [o][c], coalesced -
extern "C" __global__ void k_extract(const float* __restrict__ convw,
                                     _Float16* __restrict__ Md) {
  int q = blockIdx.x * 256 + threadIdx.x;   // 147456 float4s = 589824 floats
  float4 v = ((const float4*)convw)[q];
  float vv[4] = {v.x, v.y, v.z, v.w};
  int f = q * 4;
#pragma unroll
  for (int e = 0; e < 4; ++e) {
    int flat = f + e;                       // flat = idx*9 + 4  <=>  center tap
    if (flat % 9 == 4) Md[flat / 9] = (_Float16)vv[e];
  }
}

// ---- kernel 1: fused double scan via MFMA ---------------------------------
struct SM {
  _Float16 cy[2][256];        // y carry (f16), ping-pong
  _Float16 pad_[32];          // 64B: cz banks offset 16 vs cy
  _Float16 cz[2][256];        // z carry (f16), ping-pong
  float    sp[128 * 32];      // s-dot partials [w][32]
  float    cbuf[2][256][20];  // staged c chunks, stride 20 (pad 4) per channel
};

extern "C" __global__ void __launch_bounds__(512, 2)
k_scan(const float* __restrict__ p2, const _Float16* __restrict__ Md,
       const float* __restrict__ conv1, float* __restrict__ sout,
       float* __restrict__ stats, unsigned int* __restrict__ cnt) {
  __shared__ SM sm;
  const int tid  = threadIdx.x;
  const int l    = tid & 63;
  const int r    = tid >> 6;        // wave 0..7
  const int col  = l & 15;          // MFMA n / A-row-within-tile index
  const int quad = l >> 4;          // MFMA k-group / C-row-group index
  const int b    = blockIdx.x >> 6;
  const int h    = blockIdx.x & 63;

  if (blockIdx.x == 0 && tid == 0) { stats[0] = 0.f; stats[1] = 0.f; *cnt = 0u; }

  const bool isY = (col == 0);      // lanes holding C column 0 (y results)
  const bool isZ = (col == 1);      // lanes holding C column 1 (z results)

  // C/D rows owned by this lane: m0..m0+3 (tile 0), m1..m1+3 (tile 1)
  const int m0 = r * 32 + quad * 4;
  const int m1 = m0 + 16;

  // staging assignment: this thread covers channels ch0 and ch0+128, 4 floats
  const int ch0 = tid >> 2;
  const int q4  = (tid & 3) * 4;

  // p2_r[b][c][h][w]: channel c at pbase + c*8192 + w
  const float* pbase = p2 + (size_t)b * 2097152 + (size_t)h * 128;

  // ---- stage chunk 0 (w=0..15) ----
  {
    float4 g0 = *(const float4*)(pbase + (size_t)ch0 * 8192 + q4);
    float4 g1 = *(const float4*)(pbase + (size_t)(ch0 + 128) * 8192 + q4);
    *(float4*)(&sm.cbuf[0][ch0][q4])       = g0;
    *(float4*)(&sm.cbuf[0][ch0 + 128][q4]) = g1;
  }

  // ---- A-fragments (M, resident): lane holds A[m=tile*16+col][k=ch*32+quad*8+j]
  f16x8 A0[8], A1[8];
#pragma unroll
  for (int ch = 0; ch < 8; ++ch) {
    A0[ch] = *(const f16x8*)(Md + (size_t)(r * 32 + col) * 256 + ch * 32 + quad * 8);
    A1[ch] = *(const f16x8*)(Md + (size_t)(r * 32 + col + 16) * 256 + ch * 32 + quad * 8);
  }

  // conv1 weights at owned rows (col1 lanes)
  float vva[4], vvb[4];
  if (isZ) {
#pragma unroll
    for (int i = 0; i < 4; ++i) { vva[i] = conv1[m0 + i]; vvb[i] = conv1[m1 + i]; }
  }
  __syncthreads();   // chunk 0 visible

  // ---- init: w=0 state (z_0 = y_0 = c_0) from staged chunk 0 ----
  if (isY || isZ) {
    float c0a[4], c0b[4];
#pragma unroll
    for (int i = 0; i < 4; ++i) {
      c0a[i] = sm.cbuf[0][m0 + i][0];
      c0b[i] = sm.cbuf[0][m1 + i][0];
    }
    if (isY) {
      f16x4 pa, pb;
#pragma unroll
      for (int i = 0; i < 4; ++i) { pa[i] = (_Float16)c0a[i]; pb[i] = (_Float16)c0b[i]; }
      *(f16x4*)(sm.cy[0] + m0) = pa; *(f16x4*)(sm.cy[0] + m1) = pb;
      *(f16x4*)(sm.cz[0] + m0) = pa; *(f16x4*)(sm.cz[0] + m1) = pb;
    }
    if (isZ) {
      float p = 0.f;
#pragma unroll
      for (int i = 0; i < 4; ++i) p += vva[i] * c0a[i] + vvb[i] * c0b[i];
      sm.sp[0 * 32 + r * 4 + quad] = p;
    }
  }
  __syncthreads();   // carries visible

  // B-fragment source: lane parity picks y (even cols) / z (odd cols).
  const _Float16* selA = ((l & 1) ? sm.cz[0] : sm.cy[0]) + quad * 8;  // w odd
  const _Float16* selB = ((l & 1) ? sm.cz[1] : sm.cy[1]) + quad * 8;  // w even

#define STEP(W, SELP, WY, WZ, DOSTAGE)                                         \
  do {                                                                         \
    /* staging loads issue at step top; ds_writes sink below the MFMAs */      \
    float4 g0, g1; int t1 = 0; bool stg = false;                               \
    if (DOSTAGE) {                                                             \
      stg = (((W) & 15) == 1) && ((W) < 113);                                  \
      if (stg) {                                                               \
        t1 = ((W) >> 4) + 1;                                                   \
        g0 = *(const float4*)(pbase + (size_t)ch0 * 8192 + t1 * 16 + q4);      \
        g1 = *(const float4*)(pbase + (size_t)(ch0 + 128) * 8192 + t1 * 16 + q4);\
      }                                                                        \
    }                                                                          \
    f16x8 B[8];                                                                \
    _Pragma("unroll")                                                          \
    for (int ch = 0; ch < 8; ++ch)                                             \
      B[ch] = *(const f16x8*)((SELP) + ch * 32);                               \
    f32x4 a00 = {0.f,0.f,0.f,0.f}, a01 = {0.f,0.f,0.f,0.f};                    \
    f32x4 a10 = {0.f,0.f,0.f,0.f}, a11 = {0.f,0.f,0.f,0.f};                    \
    _Pragma("unroll")                                                          \
    for (int ch = 0; ch < 4; ++ch) {                                           \
      a00 = __builtin_amdgcn_mfma_f32_16x16x32_f16(A0[ch],   B[ch],   a00,0,0,0);\
      a10 = __builtin_amdgcn_mfma_f32_16x16x32_f16(A1[ch],   B[ch],   a10,0,0,0);\
      a01 = __builtin_amdgcn_mfma_f32_16x16x32_f16(A0[ch+4], B[ch+4], a01,0,0,0);\
      a11 = __builtin_amdgcn_mfma_f32_16x16x32_f16(A1[ch+4], B[ch+4], a11,0,0,0);\
    }                                                                          \
    f32x4 acc0 = a00 + a01, acc1 = a10 + a11;                                  \
    if (DOSTAGE && stg) {                                                      \
      float* dst = &sm.cbuf[t1 & 1][0][0];                                     \
      *(float4*)(dst + ch0 * 20 + q4)         = g0;                            \
      *(float4*)(dst + (ch0 + 128) * 20 + q4) = g1;                            \
    }                                                                          \
    const float* cptr = &sm.cbuf[((W) >> 4) & 1][0][(W) & 15];                 \
    f16x4 yh0 = {}, yh1 = {};                                                  \
    if (isY) {                                                                 \
      _Pragma("unroll")                                                        \
      for (int i = 0; i < 4; ++i) {                                            \
        yh0[i] = (_Float16)(cptr[(m0 + i) * 20] + fmaxf(acc0[i], 0.f));        \
        yh1[i] = (_Float16)(cptr[(m1 + i) * 20] + fmaxf(acc1[i], 0.f));        \
      }                                                                        \
      *(f16x4*)((WY) + m0) = yh0;                                              \
      *(f16x4*)((WY) + m1) = yh1;                                              \
    }                                                                          \
    int2 u0 = __builtin_bit_cast(int2, yh0), u1 = __builtin_bit_cast(int2, yh1);\
    u0.x = __shfl(u0.x, l & 62, 64); u0.y = __shfl(u0.y, l & 62, 64);          \
    u1.x = __shfl(u1.x, l & 62, 64); u1.y = __shfl(u1.y, l & 62, 64);          \
    f16x4 ys0 = __builtin_bit_cast(f16x4, u0), ys1 = __builtin_bit_cast(f16x4, u1);\
    if (isZ) {                                                                 \
      f16x4 zh0, zh1;                                                          \
      float p = 0.f;                                                           \
      _Pragma("unroll")                                                        \
      for (int i = 0; i < 4; ++i) {                                            \
        float z0 = (float)ys0[i] + fmaxf(acc0[i], 0.f);                        \
        float z1 = (float)ys1[i] + fmaxf(acc1[i], 0.f);                        \
        zh0[i] = (_Float16)z0; zh1[i] = (_Float16)z1;                          \
        p += vva[i] * z0 + vvb[i] * z1;                                        \
      }                                                                        \
      *(f16x4*)((WZ) + m0) = zh0;                                              \
      *(f16x4*)((WZ) + m1) = zh1;                                              \
      sm.sp[(W) * 32 + r * 4 + quad] = p;                                      \
    }                                                                          \
    __syncthreads();                                                           \
  } while (0)

#pragma unroll 1
  for (int w = 1; w < 127; w += 2) {
    STEP(w,     selA, sm.cy[1], sm.cz[1], 1);  // read buf0, write buf1 (w odd)
    STEP(w + 1, selB, sm.cy[0], sm.cz[0], 0);  // read buf1, write buf0
  }
  STEP(127, selA, sm.cy[1], sm.cz[1], 0);
#undef STEP

  // s[b,h,127-w] = dot(v, z_w): reduce the 32 partials per step
  if (tid < 128) {
    const float4* q = (const float4*)(sm.sp + tid * 32);
    float s = 0.f;
#pragma unroll
    for (int j = 0; j < 8; ++j) { float4 t4 = q[j]; s += t4.x + t4.y + t4.z + t4.w; }
    sout[(blockIdx.x << 7) + (127 - tid)] = s;
  }
}

// ---- bilinear 4x upsample (align_corners) of s: (2,64,128) -> (2,256,512) --
static __device__ __forceinline__ float bilin(const float* __restrict__ s,
                                              int idx) {
  int bb  = idx >> 17;
  int rem = idx & 131071;
  int ho  = rem >> 9;
  int wo  = rem & 511;
  const float SY = 63.0f / 255.0f, SX = 127.0f / 511.0f;
  float fy = (float)ho * SY;
  int y0 = (int)fy; int y1 = min(y0 + 1, 63); float wy = fy - (float)y0;
  float fx = (float)wo * SX;
  int x0 = (int)fx; int x1 = min(x0 + 1, 127); float wx = fx - (float)x0;
  const float* sb = s + bb * 8192;
  float cA = sb[y0 * 128 + x0] * (1.f - wy) + sb[y1 * 128 + x0] * wy;
  float cB = sb[y0 * 128 + x1] * (1.f - wy) + sb[y1 * 128 + x1] * wy;
  return cA * (1.f - wx) + cB * wx;
}

// ---- kernel 2: fused stats + normalize + sigmoid (grid-wide via counter) ---
// 256 blocks x 256 threads (grid <= CU count -> co-resident; spin is safe).
extern "C" __global__ void __launch_bounds__(256, 1)
k_statsnorm(const float* __restrict__ s, float* __restrict__ stats,
            unsigned int* __restrict__ cnt, const float* __restrict__ gamma,
            const float* __restrict__ beta, float* __restrict__ out) {
  int tid  = threadIdx.x;
  int base = blockIdx.x * 1024 + tid;
  float u[4];
  float sum = 0.f, ssq = 0.f;
#pragma unroll
  for (int i = 0; i < 4; ++i) {
    u[i] = bilin(s, base + i * 256);
    sum += u[i]; ssq += u[i] * u[i];
  }
#pragma unroll
  for (int off = 32; off > 0; off >>= 1) {
    sum += __shfl_xor(sum, off, 64);
    ssq += __shfl_xor(ssq, off, 64);
  }
  __shared__ float ls[4], lq[4];
  int wv = tid >> 6;
  if ((tid & 63) == 0) { ls[wv] = sum; lq[wv] = ssq; }
  __syncthreads();
  if (tid == 0) {
    float bsum = ls[0] + ls[1] + ls[2] + ls[3];
    float bssq = lq[0] + lq[1] + lq[2] + lq[3];
    __hip_atomic_fetch_add(&stats[0], bsum, __ATOMIC_RELAXED, __HIP_MEMORY_SCOPE_AGENT);
    __hip_atomic_fetch_add(&stats[1], bssq, __ATOMIC_RELAXED, __HIP_MEMORY_SCOPE_AGENT);
    __hip_atomic_fetch_add(cnt, 1u, __ATOMIC_RELEASE, __HIP_MEMORY_SCOPE_AGENT);
    while (__hip_atomic_load(cnt, __ATOMIC_ACQUIRE, __HIP_MEMORY_SCOPE_AGENT) < 256u)
      __builtin_amdgcn_s_sleep(8);
  }
  __syncthreads();
  float s0 = __hip_atomic_load(&stats[0], __ATOMIC_RELAXED, __HIP_MEMORY_SCOPE_AGENT);
  float s1 = __hip_atomic_load(&stats[1], __ATOMIC_RELAXED, __HIP_MEMORY_SCOPE_AGENT);
  const float invN = 1.f / 262144.f;
  float mean  = s0 * invN;
  float var   = s1 * invN - mean * mean;
  float scale = rsqrtf(var + 1e-5f) * gamma[0];
  float bias  = beta[0] - mean * scale;
#pragma unroll
  for (int i = 0; i < 4; ++i) {
    float x = u[i] * scale + bias;
    out[base + i * 256] = 1.f / (1.f + __expf(-x));
  }
}

// ---------------------------------------------------------------------------
extern "C" void kernel_launch(void* const* d_in, const int* in_sizes, int n_in,
                              void* d_out, int out_size, void* d_ws, size_t ws_size,
                              hipStream_t stream) {
  const float* p2    = (const float*)d_in[0];   // (2,256,64,128)
  const float* convw = (const float*)d_in[1];   // (256,256,1,9)
  const float* conv1 = (const float*)d_in[2];   // (1,256,1,1)
  const float* gamma = (const float*)d_in[3];   // (1,)
  const float* beta  = (const float*)d_in[4];   // (1,)
  float* out = (float*)d_out;                   // (2,1,256,512) fp32

  char* ws = (char*)d_ws;
  float*        s     = (float*)ws;             // 16384 floats  [0, 64KB)
  float*        stats = (float*)(ws + 65536);   // 2 floats
  unsigned int* cnt   = (unsigned int*)(ws + 65544);
  _Float16*     Md    = (_Float16*)(ws + 65792);// 65536 f16 (128 KB)

  hipLaunchKernelGGL(k_extract,   dim3(576), dim3(256), 0, stream, convw, Md);
  hipLaunchKernelGGL(k_scan,      dim3(128), dim3(512), 0, stream,
                     p2, Md, conv1, s, stats, cnt);
  hipLaunchKernelGGL(k_statsnorm, dim3(256), dim3(256), 0, stream,
                     s, stats, cnt, gamma, beta, out);
}

// Round 7
// 196.552 us; speedup vs baseline: 1.1334x; 1.0091x over previous
//
#include <hip/hip_runtime.h>

// ---------------------------------------------------------------------------
// R_SCNN: two width-direction SCNN scans fused into one 127-step recurrence
// via MFMA (one barrier/step), 1x1-conv channel-dot folded into the scan,
// then 4x bilinear upsample + global BN + sigmoid.
//
//   y_w = c_w + relu(M y_{w-1}),  z_w = y_w + relu(M z_{w-1}),  z_0 = y_0 = c_0
//   s[b,h,p] = dot(v, z_{127-p});  out = sigmoid(BN(upsample4(s)))
//
// Round-7: LDS-pipe diet. R6 post-mortem: step time is LDS-instruction-
// throughput-bound (~170 LDS instr/step/CU + 32 ds_bpermute from __shfl).
//  - 4 waves x 4 row-tiles (was 8 x 2): B-fragment reads halve (all waves
//    read identical B), MFMA issue per SIMD unchanged (1 wave x 32 vs 2 x 16).
//  - c_w staged TRANSPOSED cbuf[buf][w][ch]: per-step c-read = 4 broadcast
//    ds_read_b128 (all col-lanes same address -> conflict-free broadcast),
//    letting yh be computed unmasked in every lane.
//  - yn -> zn lane hop via DPP quad_perm (VALU pipe) instead of ds_bpermute.
//  - sp rows padded to 20 floats (final-reduce bank spread).
// ---------------------------------------------------------------------------

typedef _Float16 f16x8 __attribute__((ext_vector_type(8)));
typedef _Float16 f16x4 __attribute__((ext_vector_type(4)));
typedef float    f32x4 __attribute__((ext_vector_type(4)));

// swap adjacent lane pairs (0<->1, 2<->3, ...) on the VALU pipe
static __device__ __forceinline__ int xchg_pair(int x) {
#if __has_builtin(__builtin_amdgcn_update_dpp)
  return __builtin_amdgcn_update_dpp(x, x, 0xB1, 0xF, 0xF, true); // quad_perm(1,0,3,2)
#else
  return __shfl_xor(x, 1, 64);
#endif
}

// ---- kernel 0: extract center tap of conv_w -> dense f16 [o][c], coalesced -
extern "C" __global__ void k_extract(const float* __restrict__ convw,
                                     _Float16* __restrict__ Md) {
  int q = blockIdx.x * 256 + threadIdx.x;   // 147456 float4s = 589824 floats
  float4 v = ((const float4*)convw)[q];
  float vv[4] = {v.x, v.y, v.z, v.w};
  int f = q * 4;
#pragma unroll
  for (int e = 0; e < 4; ++e) {
    int flat = f + e;                       // flat = idx*9 + 4  <=>  center tap
    if (flat % 9 == 4) Md[flat / 9] = (_Float16)vv[e];
  }
}

// ---- kernel 1: fused double scan via MFMA, 4 waves ------------------------
struct SM {
  _Float16 cy[2][256];        // y carry (f16), ping-pong
  _Float16 pad0[32];          // 64B: cz banks offset 16 vs cy
  _Float16 cz[2][256];        // z carry (f16), ping-pong
  _Float16 pad1[32];
  float    cbuf[2][16][256];  // staged c, TRANSPOSED: [buf][wsub][ch]
  float    sp[128][20];       // s-dot partials, padded row (16 used)
};

extern "C" __global__ void __launch_bounds__(256, 1)
k_scan(const float* __restrict__ p2, const _Float16* __restrict__ Md,
       const float* __restrict__ conv1, float* __restrict__ sout,
       float* __restrict__ stats, unsigned int* __restrict__ cnt) {
  __shared__ SM sm;
  const int tid  = threadIdx.x;
  const int l    = tid & 63;
  const int r    = tid >> 6;        // wave 0..3, owns rows r*64 .. r*64+63
  const int col  = l & 15;          // MFMA n index
  const int quad = l >> 4;          // MFMA k-group / C-row-group
  const int b    = blockIdx.x >> 6;
  const int h    = blockIdx.x & 63;

  if (blockIdx.x == 0 && tid == 0) { stats[0] = 0.f; stats[1] = 0.f; *cnt = 0u; }

  const bool isY = (col == 0);
  const bool isZ = (col == 1);
  const int  mq  = r * 64 + quad * 4;   // lane's row base (tile t adds t*16)

  // p2_r[b][c][h][w]: channel c at pbase + c*8192 + w
  const float* pbase = p2 + (size_t)b * 2097152 + (size_t)h * 128;

  // ---- stage chunk 0 (w=0..15), thread covers channel ch = tid ----
  {
    const f32x4* g = (const f32x4*)(pbase + (size_t)tid * 8192);
    f32x4 g0 = g[0], g1 = g[1], g2 = g[2], g3 = g[3];
#pragma unroll
    for (int j = 0; j < 4; ++j) {
      sm.cbuf[0][j][tid]      = g0[j];
      sm.cbuf[0][4 + j][tid]  = g1[j];
      sm.cbuf[0][8 + j][tid]  = g2[j];
      sm.cbuf[0][12 + j][tid] = g3[j];
    }
  }

  // ---- A-fragments (resident): lane holds A[m=r*64+t*16+col][k=ch*32+quad*8+j]
  f16x8 A[4][8];
#pragma unroll
  for (int t = 0; t < 4; ++t)
#pragma unroll
    for (int ch = 0; ch < 8; ++ch)
      A[t][ch] = *(const f16x8*)(Md + (size_t)(r * 64 + t * 16 + col) * 256 +
                                 ch * 32 + quad * 8);

  // conv1 weights at this lane's rows (used by col1 lanes)
  float vvf[16];
#pragma unroll
  for (int t = 0; t < 4; ++t) {
    f32x4 vt = *(const f32x4*)(conv1 + mq + t * 16);
#pragma unroll
    for (int i = 0; i < 4; ++i) vvf[t * 4 + i] = vt[i];
  }
  __syncthreads();   // chunk 0 visible

  // ---- init: w=0 state (z_0 = y_0 = c_0) from staged chunk 0 ----
  {
    f32x4 c0[4];
#pragma unroll
    for (int t = 0; t < 4; ++t)
      c0[t] = *(const f32x4*)(&sm.cbuf[0][0][mq + t * 16]);   // broadcast read
    if (isY) {
#pragma unroll
      for (int t = 0; t < 4; ++t) {
        f16x4 p;
#pragma unroll
        for (int i = 0; i < 4; ++i) p[i] = (_Float16)c0[t][i];
        *(f16x4*)(sm.cy[0] + mq + t * 16) = p;
        *(f16x4*)(sm.cz[0] + mq + t * 16) = p;
      }
    }
    if (isZ) {
      float p = 0.f;
#pragma unroll
      for (int t = 0; t < 4; ++t)
#pragma unroll
        for (int i = 0; i < 4; ++i) p += vvf[t * 4 + i] * c0[t][i];
      sm.sp[0][r * 4 + quad] = p;
    }
  }
  __syncthreads();   // carries visible

  // B-fragment source: lane parity picks y (even cols) / z (odd cols).
  const _Float16* selA = ((l & 1) ? sm.cz[0] : sm.cy[0]) + quad * 8;  // w odd
  const _Float16* selB = ((l & 1) ? sm.cz[1] : sm.cy[1]) + quad * 8;  // w even

#define STEP(W, SELP, WY, WZ, DOSTAGE)                                         \
  do {                                                                         \
    f32x4 g0, g1, g2, g3;                                                      \
    bool stg = (DOSTAGE) && (((W) & 15) == 1) && ((W) < 113);                  \
    int t1 = ((W) >> 4) + 1;                                                   \
    if (stg) {                                                                 \
      const f32x4* g = (const f32x4*)(pbase + (size_t)tid * 8192 + t1 * 16);   \
      g0 = g[0]; g1 = g[1]; g2 = g[2]; g3 = g[3];                              \
    }                                                                          \
    f16x8 B[8];                                                                \
    _Pragma("unroll")                                                          \
    for (int ch = 0; ch < 8; ++ch)                                             \
      B[ch] = *(const f16x8*)((SELP) + ch * 32);                               \
    const float* cb = &sm.cbuf[((W) >> 4) & 1][(W) & 15][0];                   \
    f32x4 cr[4];                                                               \
    _Pragma("unroll")                                                          \
    for (int t = 0; t < 4; ++t)                                                \
      cr[t] = *(const f32x4*)(cb + mq + t * 16);   /* broadcast, all lanes */  \
    f32x4 acc[4];                                                              \
    _Pragma("unroll")                                                          \
    for (int t = 0; t < 4; ++t) {                                              \
      f32x4 p0 = {0.f, 0.f, 0.f, 0.f}, p1 = {0.f, 0.f, 0.f, 0.f};             \
      p0 = __builtin_amdgcn_mfma_f32_16x16x32_f16(A[t][0], B[0], p0, 0, 0, 0); \
      p1 = __builtin_amdgcn_mfma_f32_16x16x32_f16(A[t][4], B[4], p1, 0, 0, 0); \
      p0 = __builtin_amdgcn_mfma_f32_16x16x32_f16(A[t][1], B[1], p0, 0, 0, 0); \
      p1 = __builtin_amdgcn_mfma_f32_16x16x32_f16(A[t][5], B[5], p1, 0, 0, 0); \
      p0 = __builtin_amdgcn_mfma_f32_16x16x32_f16(A[t][2], B[2], p0, 0, 0, 0); \
      p1 = __builtin_amdgcn_mfma_f32_16x16x32_f16(A[t][6], B[6], p1, 0, 0, 0); \
      p0 = __builtin_amdgcn_mfma_f32_16x16x32_f16(A[t][3], B[3], p0, 0, 0, 0); \
      p1 = __builtin_amdgcn_mfma_f32_16x16x32_f16(A[t][7], B[7], p1, 0, 0, 0); \
      acc[t] = p0 + p1;                                                        \
    }                                                                          \
    /* y-candidate in ALL lanes (meaningful where col==0) */                   \
    f16x4 yh[4], ys[4];                                                        \
    _Pragma("unroll")                                                          \
    for (int t = 0; t < 4; ++t) {                                              \
      _Pragma("unroll")                                                        \
      for (int i = 0; i < 4; ++i)                                              \
        yh[t][i] = (_Float16)(cr[t][i] + fmaxf(acc[t][i], 0.f));               \
      int2 u = __builtin_bit_cast(int2, yh[t]);                                \
      u.x = xchg_pair(u.x); u.y = xchg_pair(u.y);                              \
      ys[t] = __builtin_bit_cast(f16x4, u);      /* col1 now holds col0's yn */\
    }                                                                          \
    if (isY) {                                                                 \
      _Pragma("unroll")                                                        \
      for (int t = 0; t < 4; ++t)                                              \
        *(f16x4*)((WY) + mq + t * 16) = yh[t];                                 \
    }                                                                          \
    if (isZ) {                                                                 \
      float p = 0.f;                                                           \
      _Pragma("unroll")                                                        \
      for (int t = 0; t < 4; ++t) {                                            \
        f16x4 zh;                                                              \
        _Pragma("unroll")                                                      \
        for (int i = 0; i < 4; ++i) {                                          \
          float z = (float)ys[t][i] + fmaxf(acc[t][i], 0.f);                   \
          zh[i] = (_Float16)z;                                                 \
          p += vvf[t * 4 + i] * z;                                             \
        }                                                                      \
        *(f16x4*)((WZ) + mq + t * 16) = zh;                                    \
      }                                                                        \
      sm.sp[(W)][r * 4 + quad] = p;                                            \
    }                                                                          \
    if (stg) {                                                                 \
      int bs = t1 & 1;                                                         \
      _Pragma("unroll")                                                        \
      for (int j = 0; j < 4; ++j) {                                            \
        sm.cbuf[bs][j][tid]      = g0[j];                                      \
        sm.cbuf[bs][4 + j][tid]  = g1[j];                                      \
        sm.cbuf[bs][8 + j][tid]  = g2[j];                                      \
        sm.cbuf[bs][12 + j][tid] = g3[j];                                      \
      }                                                                        \
    }                                                                          \
    __syncthreads();                                                           \
  } while (0)

#pragma unroll 1
  for (int w = 1; w < 127; w += 2) {
    STEP(w,     selA, sm.cy[1], sm.cz[1], 1);  // read buf0, write buf1 (w odd)
    STEP(w + 1, selB, sm.cy[0], sm.cz[0], 0);  // read buf1, write buf0
  }
  STEP(127, selA, sm.cy[1], sm.cz[1], 0);
#undef STEP

  // s[b,h,127-w] = dot(v, z_w): reduce the 16 partials per step
  if (tid < 128) {
    const f32x4* q = (const f32x4*)(sm.sp[tid]);
    f32x4 q0 = q[0], q1 = q[1], q2 = q[2], q3 = q[3];
    float s = q0[0] + q0[1] + q0[2] + q0[3] + q1[0] + q1[1] + q1[2] + q1[3] +
              q2[0] + q2[1] + q2[2] + q2[3] + q3[0] + q3[1] + q3[2] + q3[3];
    sout[(blockIdx.x << 7) + (127 - tid)] = s;
  }
}

// ---- bilinear 4x upsample (align_corners) of s: (2,64,128) -> (2,256,512) --
static __device__ __forceinline__ float bilin(const float* __restrict__ s,
                                              int idx) {
  int bb  = idx >> 17;
  int rem = idx & 131071;
  int ho  = rem >> 9;
  int wo  = rem & 511;
  const float SY = 63.0f / 255.0f, SX = 127.0f / 511.0f;
  float fy = (float)ho * SY;
  int y0 = (int)fy; int y1 = min(y0 + 1, 63); float wy = fy - (float)y0;
  float fx = (float)wo * SX;
  int x0 = (int)fx; int x1 = min(x0 + 1, 127); float wx = fx - (float)x0;
  const float* sb = s + bb * 8192;
  float cA = sb[y0 * 128 + x0] * (1.f - wy) + sb[y1 * 128 + x0] * wy;
  float cB = sb[y0 * 128 + x1] * (1.f - wy) + sb[y1 * 128 + x1] * wy;
  return cA * (1.f - wx) + cB * wx;
}

// ---- kernel 2: fused stats + normalize + sigmoid (grid-wide via counter) ---
extern "C" __global__ void __launch_bounds__(256, 1)
k_statsnorm(const float* __restrict__ s, float* __restrict__ stats,
            unsigned int* __restrict__ cnt, const float* __restrict__ gamma,
            const float* __restrict__ beta, float* __restrict__ out) {
  int tid  = threadIdx.x;
  int base = blockIdx.x * 1024 + tid;
  float u[4];
  float sum = 0.f, ssq = 0.f;
#pragma unroll
  for (int i = 0; i < 4; ++i) {
    u[i] = bilin(s, base + i * 256);
    sum += u[i]; ssq += u[i] * u[i];
  }
#pragma unroll
  for (int off = 32; off > 0; off >>= 1) {
    sum += __shfl_xor(sum, off, 64);
    ssq += __shfl_xor(ssq, off, 64);
  }
  __shared__ float ls[4], lq[4];
  int wv = tid >> 6;
  if ((tid & 63) == 0) { ls[wv] = sum; lq[wv] = ssq; }
  __syncthreads();
  if (tid == 0) {
    float bsum = ls[0] + ls[1] + ls[2] + ls[3];
    float bssq = lq[0] + lq[1] + lq[2] + lq[3];
    __hip_atomic_fetch_add(&stats[0], bsum, __ATOMIC_RELAXED, __HIP_MEMORY_SCOPE_AGENT);
    __hip_atomic_fetch_add(&stats[1], bssq, __ATOMIC_RELAXED, __HIP_MEMORY_SCOPE_AGENT);
    __hip_atomic_fetch_add(cnt, 1u, __ATOMIC_RELEASE, __HIP_MEMORY_SCOPE_AGENT);
    while (__hip_atomic_load(cnt, __ATOMIC_ACQUIRE, __HIP_MEMORY_SCOPE_AGENT) < 256u)
      __builtin_amdgcn_s_sleep(8);
  }
  __syncthreads();
  float s0 = __hip_atomic_load(&stats[0], __ATOMIC_RELAXED, __HIP_MEMORY_SCOPE_AGENT);
  float s1 = __hip_atomic_load(&stats[1], __ATOMIC_RELAXED, __HIP_MEMORY_SCOPE_AGENT);
  const float invN = 1.f / 262144.f;
  float mean  = s0 * invN;
  float var   = s1 * invN - mean * mean;
  float scale = rsqrtf(var + 1e-5f) * gamma[0];
  float bias  = beta[0] - mean * scale;
#pragma unroll
  for (int i = 0; i < 4; ++i) {
    float x = u[i] * scale + bias;
    out[base + i * 256] = 1.f / (1.f + __expf(-x));
  }
}

// ---------------------------------------------------------------------------
extern "C" void kernel_launch(void* const* d_in, const int* in_sizes, int n_in,
                              void* d_out, int out_size, void* d_ws, size_t ws_size,
                              hipStream_t stream) {
  const float* p2    = (const float*)d_in[0];   // (2,256,64,128)
  const float* convw = (const float*)d_in[1];   // (256,256,1,9)
  const float* conv1 = (const float*)d_in[2];   // (1,256,1,1)
  const float* gamma = (const float*)d_in[3];   // (1,)
  const float* beta  = (const float*)d_in[4];   // (1,)
  float* out = (float*)d_out;                   // (2,1,256,512) fp32

  char* ws = (char*)d_ws;
  float*        s     = (float*)ws;             // 16384 floats  [0, 64KB)
  float*        stats = (float*)(ws + 65536);   // 2 floats
  unsigned int* cnt   = (unsigned int*)(ws + 65544);
  _Float16*     Md    = (_Float16*)(ws + 65792);// 65536 f16 (128 KB)

  hipLaunchKernelGGL(k_extract,   dim3(576), dim3(256), 0, stream, convw, Md);
  hipLaunchKernelGGL(k_scan,      dim3(128), dim3(256), 0, stream,
                     p2, Md, conv1, s, stats, cnt);
  hipLaunchKernelGGL(k_statsnorm, dim3(256), dim3(256), 0, stream,
                     s, stats, cnt, gamma, beta, out);
}